// Round 9
// baseline (724.365 us; speedup 1.0000x reference)
//
#include <hip/hip_runtime.h>

#define USER_NUM 100000
#define ITEM_NUM 50000
#define DD 64
#define NEDGE 3200000
#define NB 16384
#define NSLOT 256

#define ATILE 8192
#define NTILE ((NEDGE + ATILE - 1) / ATILE)      // 391
#define USH 9                                    // user coarse bucket = 512 dests
#define ISH 8                                    // item coarse bucket = 256 dests
#define UBK ((USER_NUM + (1 << USH) - 1) >> USH) // 196
#define IBK ((ITEM_NUM + (1 << ISH) - 1) >> ISH) // 196
#define NBK (UBK + IBK)                          // 392
#define CPAD 16                                  // cursor padding: 1 int per 64B line
#define HIST_GRID 784

#define FP8_SCALE 64.0f   // all fp8 tables hold value*64 (avoids e4m3 subnormals)

typedef float v2f __attribute__((ext_vector_type(2)));

__device__ __forceinline__ float waveReduceSum(float x) {
#pragma unroll
    for (int off = 32; off > 0; off >>= 1)
        x += __shfl_down(x, off, 64);
    return x;
}

__device__ __forceinline__ unsigned roundbf(unsigned y) {  // fp32 bits -> bf16 bits (RNE)
    return (y + 0x7fffu + ((y >> 16) & 1u)) >> 16;
}

// ---- fp8 e4m3 helpers (HW cvt; 8 fp8 in a uint2) ----
__device__ __forceinline__ void dec8(const uint2 b, float* f) {
    v2f f0 = __builtin_amdgcn_cvt_pk_f32_fp8(b.x, false);
    v2f f1 = __builtin_amdgcn_cvt_pk_f32_fp8(b.x, true);
    v2f f2 = __builtin_amdgcn_cvt_pk_f32_fp8(b.y, false);
    v2f f3 = __builtin_amdgcn_cvt_pk_f32_fp8(b.y, true);
    f[0] = f0.x; f[1] = f0.y; f[2] = f1.x; f[3] = f1.y;
    f[4] = f2.x; f[5] = f2.y; f[6] = f3.x; f[7] = f3.y;
}
__device__ __forceinline__ void fma8(const uint2 b, const float v, float* a) {
    v2f f0 = __builtin_amdgcn_cvt_pk_f32_fp8(b.x, false);
    v2f f1 = __builtin_amdgcn_cvt_pk_f32_fp8(b.x, true);
    v2f f2 = __builtin_amdgcn_cvt_pk_f32_fp8(b.y, false);
    v2f f3 = __builtin_amdgcn_cvt_pk_f32_fp8(b.y, true);
    a[0] += v * f0.x; a[1] += v * f0.y; a[2] += v * f1.x; a[3] += v * f1.y;
    a[4] += v * f2.x; a[5] += v * f2.y; a[6] += v * f3.x; a[7] += v * f3.y;
}
__device__ __forceinline__ uint2 pack_fp8x8(const float* a) {
    int lo = 0, hi = 0;
    lo = __builtin_amdgcn_cvt_pk_fp8_f32(a[0], a[1], lo, false);
    lo = __builtin_amdgcn_cvt_pk_fp8_f32(a[2], a[3], lo, true);
    hi = __builtin_amdgcn_cvt_pk_fp8_f32(a[4], a[5], hi, false);
    hi = __builtin_amdgcn_cvt_pk_fp8_f32(a[6], a[7], hi, true);
    return make_uint2((unsigned)lo, (unsigned)hi);
}

// fp32 table -> fp8 table, scaled by FP8_SCALE. One thread = 8 features.
__global__ void __launch_bounds__(256) cvt8_kernel(
    const float4* __restrict__ src, uint2* __restrict__ dst, int n8) {
    int t = blockIdx.x * blockDim.x + threadIdx.x;
    if (t < n8) {
        float4 a = src[2 * t], b = src[2 * t + 1];
        float f[8] = {a.x * FP8_SCALE, a.y * FP8_SCALE, a.z * FP8_SCALE, a.w * FP8_SCALE,
                      b.x * FP8_SCALE, b.y * FP8_SCALE, b.z * FP8_SCALE, b.w * FP8_SCALE};
        dst[t] = pack_fp8x8(f);
    }
}

// ---------- two-level binned counting sort ----------

__global__ void __launch_bounds__(256) coarse_hist(
    const int4* __restrict__ eu4, const int4* __restrict__ ei4,
    int* __restrict__ coarseCnt) {
    __shared__ int lc[NBK];
    const int t = threadIdx.x;
    for (int j = t; j < NBK; j += 256) lc[j] = 0;
    __syncthreads();
    for (int k = blockIdx.x * 256 + t; k < NEDGE / 4; k += HIST_GRID * 256) {
        int4 u = eu4[k];
        int4 i = ei4[k];
        atomicAdd(&lc[u.x >> USH], 1); atomicAdd(&lc[u.y >> USH], 1);
        atomicAdd(&lc[u.z >> USH], 1); atomicAdd(&lc[u.w >> USH], 1);
        atomicAdd(&lc[UBK + (i.x >> ISH)], 1); atomicAdd(&lc[UBK + (i.y >> ISH)], 1);
        atomicAdd(&lc[UBK + (i.z >> ISH)], 1); atomicAdd(&lc[UBK + (i.w >> ISH)], 1);
    }
    __syncthreads();
    for (int j = t; j < NBK; j += 256)
        if (lc[j]) atomicAdd(&coarseCnt[j * CPAD], lc[j]);
}

__global__ void __launch_bounds__(512) coarse_scan(
    const int* __restrict__ cnt, int* __restrict__ base, int* __restrict__ cur) {
    __shared__ int a[512];
    const int t = threadIdx.x;
    int v = (t < UBK) ? cnt[t * CPAD] : 0;
    a[t] = v;
    __syncthreads();
    for (int off = 1; off < 512; off <<= 1) {
        int x = (t >= off) ? a[t - off] : 0;
        __syncthreads();
        a[t] += x;
        __syncthreads();
    }
    if (t < UBK) { base[t] = a[t] - v; cur[t * CPAD] = a[t] - v; }
    __syncthreads();
    v = (t < IBK) ? cnt[(UBK + t) * CPAD] : 0;
    a[t] = v;
    __syncthreads();
    for (int off = 1; off < 512; off <<= 1) {
        int x = (t >= off) ? a[t - off] : 0;
        __syncthreads();
        a[t] += x;
        __syncthreads();
    }
    if (t < IBK) { base[UBK + t] = a[t] - v; cur[(UBK + t) * CPAD] = a[t] - v; }
}

// binA: block-level LDS counting sort per (tile, direction), then sequential
// coalesced flush per bucket run. blockIdx.y: 0 = U-direction, 1 = I-direction.
__global__ void __launch_bounds__(256) binA(
    const int* __restrict__ eu, const int* __restrict__ ei,
    const float* __restrict__ ev,
    int* __restrict__ ccur,           // padded cursors, NBK*CPAD
    int2* __restrict__ stU, int2* __restrict__ stI) {
    __shared__ unsigned short sidx[ATILE];  // LDS-sorted local edge index
    __shared__ unsigned char  sbid[ATILE];  // bucket id per sorted slot
    __shared__ int hist[256];
    __shared__ int pscan[256];
    __shared__ int cursor[256];
    __shared__ int delta[256];

    const int t = threadIdx.x;
    const int dirI = blockIdx.y;
    const int tb = blockIdx.x * ATILE;
    const int n = min(ATILE, NEDGE - tb);
    const int* key = dirI ? ei : eu;
    const int SH = dirI ? ISH : USH;

    hist[t] = 0;
    __syncthreads();
    for (int k = t; k < n; k += 256)
        atomicAdd(&hist[key[tb + k] >> SH], 1);
    __syncthreads();
    pscan[t] = hist[t];
    __syncthreads();
    for (int off = 1; off < 256; off <<= 1) {
        int x = (t >= off) ? pscan[t - off] : 0;
        __syncthreads();
        pscan[t] += x;
        __syncthreads();
    }
    {
        const int c = hist[t];
        const int lst = pscan[t] - c;
        cursor[t] = lst;
        int gp = 0;
        if (c > 0) {
            int* gc = dirI ? (ccur + UBK * CPAD) : ccur;
            gp = atomicAdd(&gc[t * CPAD], c);
        }
        delta[t] = gp - lst;
    }
    __syncthreads();
    for (int k = t; k < n; k += 256) {
        const int b = key[tb + k] >> SH;
        const int p = atomicAdd(&cursor[b], 1);
        sidx[p] = (unsigned short)k;
        sbid[p] = (unsigned char)b;
    }
    __syncthreads();
    if (dirI == 0) {
        for (int p = t; p < n; p += 256) {
            const int e = tb + sidx[p];
            const int b = sbid[p];
            const int u = eu[e], i = ei[e];
            const int vb = __float_as_int(ev[e]);
            stU[delta[b] + p] = make_int2(((u & ((1 << USH) - 1)) << 16) | i, vb);
        }
    } else {
        for (int p = t; p < n; p += 256) {
            const int e = tb + sidx[p];
            const int b = sbid[p];
            const int u = eu[e], i = ei[e];
            const int vb = __float_as_int(ev[e]);
            stI[delta[b] + p] = make_int2(((i & ((1 << ISH) - 1)) << 17) | u, vb);
        }
    }
}

__global__ void __launch_bounds__(256) binB(
    const int2* __restrict__ stU, const int2* __restrict__ stI,
    const int* __restrict__ base, const int* __restrict__ cnt,
    int* __restrict__ rpU, int* __restrict__ rpI,
    unsigned* __restrict__ ivU, unsigned* __restrict__ ivI) {
    __shared__ int h[512];
    const int t = threadIdx.x;
    const int b = blockIdx.x;
    if (b < UBK) {
        const int s = base[b], n = cnt[b * CPAD];
        const int dbase = b << USH;
        h[t] = 0; h[t + 256] = 0;
        __syncthreads();
        for (int p = s + t; p < s + n; p += 256)
            atomicAdd(&h[(unsigned)stU[p].x >> 16], 1);
        __syncthreads();
        int o0 = h[t], o1 = h[t + 256];
        for (int off = 1; off < 512; off <<= 1) {
            int x0 = (t >= off) ? h[t - off] : 0;
            int x1 = (t + 256 >= off) ? h[t + 256 - off] : 0;
            __syncthreads();
            h[t] += x0; h[t + 256] += x1;
            __syncthreads();
        }
        int e0 = s + h[t] - o0, e1 = s + h[t + 256] - o1;
        __syncthreads();
        h[t] = e0; h[t + 256] = e1;
        if (dbase + t < USER_NUM) rpU[dbase + t] = e0;
        if (dbase + 256 + t < USER_NUM) rpU[dbase + 256 + t] = e1;
        if (t == 0 && dbase + 512 >= USER_NUM) rpU[USER_NUM] = s + n;
        __syncthreads();
        for (int p = s + t; p < s + n; p += 256) {
            int2 en = stU[p];
            unsigned x = (unsigned)en.x;
            int pos = atomicAdd(&h[x >> 16], 1);
            unsigned bf = roundbf((unsigned)en.y);
            ivU[pos] = (bf << 16) | (x & 0xFFFFu);
        }
    } else {
        const int ib = b - UBK;
        const int s = base[b], n = cnt[b * CPAD];
        const int dbase = ib << ISH;
        h[t] = 0;
        __syncthreads();
        for (int p = s + t; p < s + n; p += 256)
            atomicAdd(&h[(unsigned)stI[p].x >> 17], 1);
        __syncthreads();
        int o0 = h[t];
        for (int off = 1; off < 256; off <<= 1) {
            int x0 = (t >= off) ? h[t - off] : 0;
            __syncthreads();
            h[t] += x0;
            __syncthreads();
        }
        int e0 = s + h[t] - o0;
        __syncthreads();
        h[t] = e0;
        if (dbase + t < ITEM_NUM) rpI[dbase + t] = e0;
        if (t == 0 && dbase + 256 >= ITEM_NUM) rpI[ITEM_NUM] = s + n;
        __syncthreads();
        for (int p = s + t; p < s + n; p += 256) {
            int2 en = stI[p];
            unsigned x = (unsigned)en.x;
            int pos = atomicAdd(&h[x >> 17], 1);
            unsigned v15 = roundbf((unsigned)en.y) & 0x7FFFu;
            ivI[pos] = (v15 << 17) | (x & 0x1FFFFu);
        }
    }
}

// ---------- gather hop core: fp8 source rows (64 B = 1 line), fp32 accumulate ----
template<bool ISU>
__device__ __forceinline__ void row_accum8(
    const int* __restrict__ rp, const unsigned* __restrict__ iv,
    const uint2* __restrict__ src, int row, int sub, int r, float* acc) {
    const int s = rp[row], e2 = rp[row + 1];
    float a0[8] = {0, 0, 0, 0, 0, 0, 0, 0};
    float a1[8] = {0, 0, 0, 0, 0, 0, 0, 0};
    int t = s + sub;
    for (; t + 8 < e2; t += 16) {
        const unsigned q0 = iv[t];
        const unsigned q1 = iv[t + 8];
        const float v0 = ISU ? __uint_as_float(q0 & 0xFFFF0000u)
                             : __uint_as_float((q0 >> 17) << 16);
        const float v1 = ISU ? __uint_as_float(q1 & 0xFFFF0000u)
                             : __uint_as_float((q1 >> 17) << 16);
        const int x0 = ISU ? (int)(q0 & 0xFFFFu) : (int)(q0 & 0x1FFFFu);
        const int x1 = ISU ? (int)(q1 & 0xFFFFu) : (int)(q1 & 0x1FFFFu);
        const uint2 b0 = src[x0 * 8 + r];
        const uint2 b1 = src[x1 * 8 + r];
        fma8(b0, v0, a0);
        fma8(b1, v1, a1);
    }
    if (t < e2) {
        const unsigned q0 = iv[t];
        const float v0 = ISU ? __uint_as_float(q0 & 0xFFFF0000u)
                             : __uint_as_float((q0 >> 17) << 16);
        const int x0 = ISU ? (int)(q0 & 0xFFFFu) : (int)(q0 & 0x1FFFFu);
        const uint2 b0 = src[x0 * 8 + r];
        fma8(b0, v0, a0);
    }
#pragma unroll
    for (int k = 0; k < 8; k++) acc[k] = a0[k] + a1[k];
#pragma unroll
    for (int off = 8; off <= 32; off <<= 1) {
#pragma unroll
        for (int k = 0; k < 8; k++) acc[k] += __shfl_xor(acc[k], off, 64);
    }
    // valid on sub==0
}

__global__ void __launch_bounds__(256) gather_hop_f8(
    const int* __restrict__ rpU, const unsigned* __restrict__ ivU,
    const uint2* __restrict__ srcForU, uint2* __restrict__ outU,
    const int* __restrict__ rpI, const unsigned* __restrict__ ivI,
    const uint2* __restrict__ srcForI, uint2* __restrict__ outI) {
    const int lane = threadIdx.x & 63;
    const int sub = lane >> 3;
    const int r = lane & 7;
    const int wave = blockIdx.x * 4 + (threadIdx.x >> 6);
    float acc[8];
    uint2* out; int row;
    if (wave < USER_NUM) {
        row = wave;
        row_accum8<true>(rpU, ivU, srcForU, row, sub, r, acc);
        out = outU;
    } else if (wave < USER_NUM + ITEM_NUM) {
        row = wave - USER_NUM;
        row_accum8<false>(rpI, ivI, srcForI, row, sub, r, acc);
        out = outI;
    } else return;
    if (sub == 0) out[row * 8 + r] = pack_fp8x8(acc);
}

__global__ void __launch_bounds__(256) gather_hop3(
    const int* __restrict__ rpU, const unsigned* __restrict__ ivU,
    const uint2* __restrict__ srcForU,
    const int* __restrict__ rpI, const unsigned* __restrict__ ivI,
    const uint2* __restrict__ srcForI,
    const float4* __restrict__ embU, const uint2* __restrict__ g1u,
    const uint2* __restrict__ g2u, float4* __restrict__ gcnU,
    const float4* __restrict__ embI, const uint2* __restrict__ g1i,
    const uint2* __restrict__ g2i, float4* __restrict__ gcnI) {
    const int lane = threadIdx.x & 63;
    const int sub = lane >> 3;
    const int r = lane & 7;
    const int wave = blockIdx.x * 4 + (threadIdx.x >> 6);
    float acc[8];
    const float4* emb; const uint2* g1; const uint2* g2; float4* gcn; int row;
    if (wave < USER_NUM) {
        row = wave;
        row_accum8<true>(rpU, ivU, srcForU, row, sub, r, acc);
        emb = embU; g1 = g1u; g2 = g2u; gcn = gcnU;
    } else if (wave < USER_NUM + ITEM_NUM) {
        row = wave - USER_NUM;
        row_accum8<false>(rpI, ivI, srcForI, row, sub, r, acc);
        emb = embI; g1 = g1i; g2 = g2i; gcn = gcnI;
    } else return;
    if (sub == 0) {
        const float C1 = 0.5f / FP8_SCALE;
        const float C2 = (1.0f / 3.0f) / FP8_SCALE;
        const float C3 = 0.25f / FP8_SCALE;
        float f1[8], f2[8];
        dec8(g1[row * 8 + r], f1);
        dec8(g2[row * 8 + r], f2);
        const float4 e0 = emb[row * 16 + 2 * r];
        const float4 e1 = emb[row * 16 + 2 * r + 1];
        float4 o0, o1;
        o0.x = e0.x + C1 * f1[0] + C2 * f2[0] + C3 * acc[0];
        o0.y = e0.y + C1 * f1[1] + C2 * f2[1] + C3 * acc[1];
        o0.z = e0.z + C1 * f1[2] + C2 * f2[2] + C3 * acc[2];
        o0.w = e0.w + C1 * f1[3] + C2 * f2[3] + C3 * acc[3];
        o1.x = e1.x + C1 * f1[4] + C2 * f2[4] + C3 * acc[4];
        o1.y = e1.y + C1 * f1[5] + C2 * f2[5] + C3 * acc[5];
        o1.z = e1.z + C1 * f1[6] + C2 * f2[6] + C3 * acc[6];
        o1.w = e1.w + C1 * f1[7] + C2 * f2[7] + C3 * acc[7];
        gcn[row * 16 + 2 * r] = o0;
        gcn[row * 16 + 2 * r + 1] = o1;
    }
}

// ---------- losses ----------
__global__ void __launch_bounds__(256) bpr_loss(
    const int* __restrict__ user, const int* __restrict__ itemI,
    const int* __restrict__ itemJ,
    const float4* __restrict__ gcnU4, const float4* __restrict__ gcnI4,
    float* __restrict__ accs) {
    const int lane = threadIdx.x & 63;
    const int sub = lane >> 4;
    const int r = lane & 15;
    const int W = blockIdx.x * 4 + (threadIdx.x >> 6);
    const int NW = gridDim.x * 4;
    float accB = 0.0f, accR = 0.0f;
    for (int g = W; g < NB / 4; g += NW) {
        const int samp = g * 4 + sub;
        const int uu = user[samp], vi = itemI[samp], vj = itemJ[samp];
        const float4 u  = gcnU4[uu * 16 + r];
        const float4 xi = gcnI4[vi * 16 + r];
        const float4 xj = gcnI4[vj * 16 + r];
        float pi = u.x * xi.x + u.y * xi.y + u.z * xi.z + u.w * xi.w;
        float pj = u.x * xj.x + u.y * xj.y + u.z * xj.z + u.w * xj.w;
        float rg = u.x * u.x + u.y * u.y + u.z * u.z + u.w * u.w
                 + xi.x * xi.x + xi.y * xi.y + xi.z * xi.z + xi.w * xi.w
                 + xj.x * xj.x + xj.y * xj.y + xj.z * xj.z + xj.w * xj.w;
#pragma unroll
        for (int off = 1; off <= 8; off <<= 1) {
            pi += __shfl_xor(pi, off, 64);
            pj += __shfl_xor(pj, off, 64);
            rg += __shfl_xor(rg, off, 64);
        }
        if (r == 0) {
            const float x = pi - pj;
            accB += fmaxf(-x, 0.0f) + log1pf(expf(-fabsf(x)));
            accR += rg;
        }
    }
    accB = waveReduceSum(accB);
    accR = waveReduceSum(accR);
    if (lane == 0) {
        const int slot = W & (NSLOT - 1);
        unsafeAtomicAdd(&accs[0 * NSLOT + slot], accB);
        unsafeAtomicAdd(&accs[1 * NSLOT + slot], accR);
    }
}

__global__ void __launch_bounds__(256) self_loss(
    const float4* __restrict__ oldU4, const float4* __restrict__ oldI4,
    const float4* __restrict__ gcnU4, const float4* __restrict__ gcnI4,
    const float* __restrict__ nU, const float* __restrict__ nI,
    float* __restrict__ accs) {
    const int lane = threadIdx.x & 63;
    const int sub = lane >> 4;
    const int r = lane & 15;
    const int W = blockIdx.x * 4 + (threadIdx.x >> 6);
    const int NW = gridDim.x * 4;
    const int ngroups = (USER_NUM + ITEM_NUM) / 4;
    float accU = 0.0f, accI = 0.0f;
    for (int g = W; g < ngroups; g += NW) {
        const int row = g * 4 + sub;
        const bool isU = row < USER_NUM;
        const int rr = isU ? row : row - USER_NUM;
        const float4 o  = isU ? oldU4[rr * 16 + r] : oldI4[rr * 16 + r];
        const float4 gg = isU ? gcnU4[rr * 16 + r] : gcnI4[rr * 16 + r];
        const float dx = o.x - gg.x, dy = o.y - gg.y;
        const float dz = o.z - gg.z, dw = o.w - gg.w;
        float s = dx * dx + dy * dy + dz * dz + dw * dw;
#pragma unroll
        for (int off = 1; off <= 8; off <<= 1)
            s += __shfl_xor(s, off, 64);
        if (r == 0) {
            const float val = sqrtf(s) * (isU ? nU[rr] : nI[rr]);
            if (isU) accU += val; else accI += val;
        }
    }
    accU = waveReduceSum(accU);
    accI = waveReduceSum(accI);
    if (lane == 0) {
        const int slot = W & (NSLOT - 1);
        unsafeAtomicAdd(&accs[2 * NSLOT + slot], accU);
        unsafeAtomicAdd(&accs[3 * NSLOT + slot], accI);
    }
}

__global__ void __launch_bounds__(64) finalize(const float* __restrict__ accs,
                                               float* __restrict__ out) {
    const int lane = threadIdx.x;
    float s[4];
#pragma unroll
    for (int k = 0; k < 4; k++) {
        float v = 0.0f;
        for (int j = lane; j < NSLOT; j += 64) v += accs[k * NSLOT + j];
        s[k] = waveReduceSum(v);
    }
    if (lane == 0) {
        const float loss_bpr = s[0] / NB + 1e-4f * (s[1] / NB);
        const float loss_self = s[2] / USER_NUM + s[3] / ITEM_NUM;
        out[0] = loss_bpr;
        out[1] = 100.0f * loss_self;
        out[2] = 1.0f;
        out[3] = 1.0f;
    }
}

extern "C" void kernel_launch(void* const* d_in, const int* in_sizes, int n_in,
                              void* d_out, int out_size, void* d_ws, size_t ws_size,
                              hipStream_t stream) {
    const int*   user     = (const int*)d_in[0];
    const int*   item_i   = (const int*)d_in[1];
    const int*   item_j   = (const int*)d_in[2];
    const int*   edge_u   = (const int*)d_in[3];
    const int*   edge_i   = (const int*)d_in[4];
    const float* edge_val = (const float*)d_in[5];
    const float* user_emb = (const float*)d_in[6];
    const float* item_emb = (const float*)d_in[7];
    const float* old_U    = (const float*)d_in[8];
    const float* old_I    = (const float*)d_in[9];
    const float* n_U      = (const float*)d_in[10];
    const float* n_I      = (const float*)d_in[11];
    float* out = (float*)d_out;

    char* base = (char*)d_ws;
    size_t off = 0;
    auto carve = [&](size_t bytes) {
        char* p = base + off;
        off += (bytes + 255) & ~(size_t)255;
        return p;
    };
    int*      coarseCnt = (int*)carve(NBK * CPAD * 4);  // padded: 1 count / 64B
    float*    accs      = (float*)carve(4 * NSLOT * 4);
    size_t zero_bytes = off;  // everything above must start zeroed
    int*      cbase = (int*)carve(NBK * 4);             // compact
    int*      ccur  = (int*)carve(NBK * CPAD * 4);      // padded cursors
    int*      rpU   = (int*)carve((USER_NUM + 1) * 4);
    int*      rpI   = (int*)carve((ITEM_NUM + 1) * 4);
    unsigned* ivU   = (unsigned*)carve((size_t)NEDGE * 4);
    unsigned* ivI   = (unsigned*)carve((size_t)NEDGE * 4);
    uint2*    ebU8  = (uint2*)carve((size_t)USER_NUM * DD);  // fp8 tables
    uint2*    ebI8  = (uint2*)carve((size_t)ITEM_NUM * DD);
    uint2*    g1u8  = (uint2*)carve((size_t)USER_NUM * DD);
    uint2*    g1i8  = (uint2*)carve((size_t)ITEM_NUM * DD);
    uint2*    g2u8  = (uint2*)carve((size_t)USER_NUM * DD);
    uint2*    g2i8  = (uint2*)carve((size_t)ITEM_NUM * DD);
    int2*     stU   = (int2*)carve((size_t)NEDGE * 8);   // staging, dead after binB
    int2*     stI   = (int2*)carve((size_t)NEDGE * 8);
    float* gcnU = (float*)stU;   // aliases staging (hop3 runs after binB)
    float* gcnI = (float*)stI;

    hipMemsetAsync(d_ws, 0, zero_bytes, stream);

    const dim3 blk(256);

    cvt8_kernel<<<(USER_NUM * 8 + 255) / 256, blk, 0, stream>>>(
        (const float4*)user_emb, ebU8, USER_NUM * 8);
    cvt8_kernel<<<(ITEM_NUM * 8 + 255) / 256, blk, 0, stream>>>(
        (const float4*)item_emb, ebI8, ITEM_NUM * 8);

    coarse_hist<<<HIST_GRID, blk, 0, stream>>>((const int4*)edge_u,
                                               (const int4*)edge_i, coarseCnt);
    coarse_scan<<<1, 512, 0, stream>>>(coarseCnt, cbase, ccur);
    binA<<<dim3(NTILE, 2), blk, 0, stream>>>(edge_u, edge_i, edge_val,
                                             ccur, stU, stI);
    binB<<<NBK, blk, 0, stream>>>(stU, stI, cbase, coarseCnt, rpU, rpI, ivU, ivI);

    const int rows = USER_NUM + ITEM_NUM;
    const int hop_grid = (rows + 3) / 4;

    gather_hop_f8<<<hop_grid, blk, 0, stream>>>(rpU, ivU, ebI8, g1u8,
                                                rpI, ivI, ebU8, g1i8);
    gather_hop_f8<<<hop_grid, blk, 0, stream>>>(rpU, ivU, g1i8, g2u8,
                                                rpI, ivI, g1u8, g2i8);
    gather_hop3<<<hop_grid, blk, 0, stream>>>(
        rpU, ivU, g2i8, rpI, ivI, g2u8,
        (const float4*)user_emb, g1u8, g2u8, (float4*)gcnU,
        (const float4*)item_emb, g1i8, g2i8, (float4*)gcnI);

    bpr_loss<<<128, blk, 0, stream>>>(user, item_i, item_j,
                                      (const float4*)gcnU, (const float4*)gcnI, accs);
    self_loss<<<256, blk, 0, stream>>>(
        (const float4*)old_U, (const float4*)old_I,
        (const float4*)gcnU, (const float4*)gcnI, n_U, n_I, accs);
    finalize<<<1, 64, 0, stream>>>(accs, out);
}

// Round 10
// 613.510 us; speedup vs baseline: 1.1807x; 1.1807x over previous
//
#include <hip/hip_runtime.h>

#define USER_NUM 100000
#define ITEM_NUM 50000
#define DD 64
#define NEDGE 3200000
#define NB 16384
#define NSLOT 256

#define ATILE 8192
#define NTILE ((NEDGE + ATILE - 1) / ATILE)      // 391
#define USH 9                                    // user coarse bucket = 512 dests
#define ISH 8                                    // item coarse bucket = 256 dests
#define UBK ((USER_NUM + (1 << USH) - 1) >> USH) // 196
#define IBK ((ITEM_NUM + (1 << ISH) - 1) >> ISH) // 196
#define NBK (UBK + IBK)                          // 392
#define CPAD 16                                  // cursor padding: 1 int per 64B line
#define HIST_GRID 784

#define FP8_SCALE 64.0f   // all fp8 tables hold value*64 (avoids e4m3 subnormals)

typedef float v2f __attribute__((ext_vector_type(2)));

__device__ __forceinline__ float waveReduceSum(float x) {
#pragma unroll
    for (int off = 32; off > 0; off >>= 1)
        x += __shfl_down(x, off, 64);
    return x;
}

__device__ __forceinline__ unsigned roundbf(unsigned y) {  // fp32 bits -> bf16 bits (RNE)
    return (y + 0x7fffu + ((y >> 16) & 1u)) >> 16;
}

// ---- fp8 e4m3 helpers (HW cvt; 8 fp8 in a uint2) ----
__device__ __forceinline__ void dec8(const uint2 b, float* f) {
    v2f f0 = __builtin_amdgcn_cvt_pk_f32_fp8(b.x, false);
    v2f f1 = __builtin_amdgcn_cvt_pk_f32_fp8(b.x, true);
    v2f f2 = __builtin_amdgcn_cvt_pk_f32_fp8(b.y, false);
    v2f f3 = __builtin_amdgcn_cvt_pk_f32_fp8(b.y, true);
    f[0] = f0.x; f[1] = f0.y; f[2] = f1.x; f[3] = f1.y;
    f[4] = f2.x; f[5] = f2.y; f[6] = f3.x; f[7] = f3.y;
}
__device__ __forceinline__ void fma8(const uint2 b, const float v, float* a) {
    v2f f0 = __builtin_amdgcn_cvt_pk_f32_fp8(b.x, false);
    v2f f1 = __builtin_amdgcn_cvt_pk_f32_fp8(b.x, true);
    v2f f2 = __builtin_amdgcn_cvt_pk_f32_fp8(b.y, false);
    v2f f3 = __builtin_amdgcn_cvt_pk_f32_fp8(b.y, true);
    a[0] += v * f0.x; a[1] += v * f0.y; a[2] += v * f1.x; a[3] += v * f1.y;
    a[4] += v * f2.x; a[5] += v * f2.y; a[6] += v * f3.x; a[7] += v * f3.y;
}
__device__ __forceinline__ uint2 pack_fp8x8(const float* a) {
    int lo = 0, hi = 0;
    lo = __builtin_amdgcn_cvt_pk_fp8_f32(a[0], a[1], lo, false);
    lo = __builtin_amdgcn_cvt_pk_fp8_f32(a[2], a[3], lo, true);
    hi = __builtin_amdgcn_cvt_pk_fp8_f32(a[4], a[5], hi, false);
    hi = __builtin_amdgcn_cvt_pk_fp8_f32(a[6], a[7], hi, true);
    return make_uint2((unsigned)lo, (unsigned)hi);
}

// fp32 table -> fp8 table, scaled by FP8_SCALE. One thread = 8 features.
__global__ void __launch_bounds__(256) cvt8_kernel(
    const float4* __restrict__ src, uint2* __restrict__ dst, int n8) {
    int t = blockIdx.x * blockDim.x + threadIdx.x;
    if (t < n8) {
        float4 a = src[2 * t], b = src[2 * t + 1];
        float f[8] = {a.x * FP8_SCALE, a.y * FP8_SCALE, a.z * FP8_SCALE, a.w * FP8_SCALE,
                      b.x * FP8_SCALE, b.y * FP8_SCALE, b.z * FP8_SCALE, b.w * FP8_SCALE};
        dst[t] = pack_fp8x8(f);
    }
}

// ---------- two-level binned counting sort ----------

__global__ void __launch_bounds__(256) coarse_hist(
    const int4* __restrict__ eu4, const int4* __restrict__ ei4,
    int* __restrict__ coarseCnt) {
    __shared__ int lc[NBK];
    const int t = threadIdx.x;
    for (int j = t; j < NBK; j += 256) lc[j] = 0;
    __syncthreads();
    for (int k = blockIdx.x * 256 + t; k < NEDGE / 4; k += HIST_GRID * 256) {
        int4 u = eu4[k];
        int4 i = ei4[k];
        atomicAdd(&lc[u.x >> USH], 1); atomicAdd(&lc[u.y >> USH], 1);
        atomicAdd(&lc[u.z >> USH], 1); atomicAdd(&lc[u.w >> USH], 1);
        atomicAdd(&lc[UBK + (i.x >> ISH)], 1); atomicAdd(&lc[UBK + (i.y >> ISH)], 1);
        atomicAdd(&lc[UBK + (i.z >> ISH)], 1); atomicAdd(&lc[UBK + (i.w >> ISH)], 1);
    }
    __syncthreads();
    for (int j = t; j < NBK; j += 256)
        if (lc[j]) atomicAdd(&coarseCnt[j * CPAD], lc[j]);
}

__global__ void __launch_bounds__(512) coarse_scan(
    const int* __restrict__ cnt, int* __restrict__ base, int* __restrict__ cur) {
    __shared__ int a[512];
    const int t = threadIdx.x;
    int v = (t < UBK) ? cnt[t * CPAD] : 0;
    a[t] = v;
    __syncthreads();
    for (int off = 1; off < 512; off <<= 1) {
        int x = (t >= off) ? a[t - off] : 0;
        __syncthreads();
        a[t] += x;
        __syncthreads();
    }
    if (t < UBK) { base[t] = a[t] - v; cur[t * CPAD] = a[t] - v; }
    __syncthreads();
    v = (t < IBK) ? cnt[(UBK + t) * CPAD] : 0;
    a[t] = v;
    __syncthreads();
    for (int off = 1; off < 512; off <<= 1) {
        int x = (t >= off) ? a[t - off] : 0;
        __syncthreads();
        a[t] += x;
        __syncthreads();
    }
    if (t < IBK) { base[UBK + t] = a[t] - v; cur[(UBK + t) * CPAD] = a[t] - v; }
}

// binA: block-level LDS counting sort per (tile, direction). Payload is built
// and sorted entirely in LDS (no permuted global re-read — R9 lesson), then
// flushed sequentially so global writes are wave-coalesced full lines.
// blockIdx.y: 0 = U-direction, 1 = I-direction.
__global__ void __launch_bounds__(256, 2) binA(
    const int* __restrict__ eu, const int* __restrict__ ei,
    const float* __restrict__ ev,
    int* __restrict__ ccur,           // padded cursors, NBK*CPAD
    int2* __restrict__ stU, int2* __restrict__ stI) {
    __shared__ int2 pay[ATILE];             // 64 KB sorted payload
    __shared__ unsigned char sbid[ATILE];   // 8 KB bucket id per slot
    __shared__ int hist[256];
    __shared__ int pscan[256];
    __shared__ int cursor[256];
    __shared__ int delta[256];

    const int t = threadIdx.x;
    const int dirI = blockIdx.y;
    const int tb = blockIdx.x * ATILE;
    const int n = min(ATILE, NEDGE - tb);
    const int* key = dirI ? ei : eu;
    const int SH = dirI ? ISH : USH;

    hist[t] = 0;
    __syncthreads();
    for (int k = t; k < n; k += 256)
        atomicAdd(&hist[key[tb + k] >> SH], 1);
    __syncthreads();
    pscan[t] = hist[t];
    __syncthreads();
    for (int off = 1; off < 256; off <<= 1) {
        int x = (t >= off) ? pscan[t - off] : 0;
        __syncthreads();
        pscan[t] += x;
        __syncthreads();
    }
    {
        const int c = hist[t];
        const int lst = pscan[t] - c;
        cursor[t] = lst;
        int gp = 0;
        if (c > 0) {
            int* gc = dirI ? (ccur + UBK * CPAD) : ccur;
            gp = atomicAdd(&gc[t * CPAD], c);
        }
        delta[t] = gp - lst;
    }
    __syncthreads();
    // scatter payload into sorted LDS slots; edge stream read is linear
    if (dirI == 0) {
        for (int k = t; k < n; k += 256) {
            const int e = tb + k;
            const int u = eu[e], i = ei[e];
            const int b = u >> USH;
            const int p = atomicAdd(&cursor[b], 1);
            pay[p] = make_int2(((u & ((1 << USH) - 1)) << 16) | i,
                               __float_as_int(ev[e]));
            sbid[p] = (unsigned char)b;
        }
    } else {
        for (int k = t; k < n; k += 256) {
            const int e = tb + k;
            const int u = eu[e], i = ei[e];
            const int b = i >> ISH;
            const int p = atomicAdd(&cursor[b], 1);
            pay[p] = make_int2(((i & ((1 << ISH) - 1)) << 17) | u,
                               __float_as_int(ev[e]));
            sbid[p] = (unsigned char)b;
        }
    }
    __syncthreads();
    // sequential flush: consecutive threads -> consecutive global addresses
    int2* st = dirI ? stI : stU;
    for (int p = t; p < n; p += 256)
        st[delta[sbid[p]] + p] = pay[p];
}

__global__ void __launch_bounds__(256) binB(
    const int2* __restrict__ stU, const int2* __restrict__ stI,
    const int* __restrict__ base, const int* __restrict__ cnt,
    int* __restrict__ rpU, int* __restrict__ rpI,
    unsigned* __restrict__ ivU, unsigned* __restrict__ ivI) {
    __shared__ int h[512];
    const int t = threadIdx.x;
    const int b = blockIdx.x;
    if (b < UBK) {
        const int s = base[b], n = cnt[b * CPAD];
        const int dbase = b << USH;
        h[t] = 0; h[t + 256] = 0;
        __syncthreads();
        for (int p = s + t; p < s + n; p += 256)
            atomicAdd(&h[(unsigned)stU[p].x >> 16], 1);
        __syncthreads();
        int o0 = h[t], o1 = h[t + 256];
        for (int off = 1; off < 512; off <<= 1) {
            int x0 = (t >= off) ? h[t - off] : 0;
            int x1 = (t + 256 >= off) ? h[t + 256 - off] : 0;
            __syncthreads();
            h[t] += x0; h[t + 256] += x1;
            __syncthreads();
        }
        int e0 = s + h[t] - o0, e1 = s + h[t + 256] - o1;
        __syncthreads();
        h[t] = e0; h[t + 256] = e1;
        if (dbase + t < USER_NUM) rpU[dbase + t] = e0;
        if (dbase + 256 + t < USER_NUM) rpU[dbase + 256 + t] = e1;
        if (t == 0 && dbase + 512 >= USER_NUM) rpU[USER_NUM] = s + n;
        __syncthreads();
        for (int p = s + t; p < s + n; p += 256) {
            int2 en = stU[p];
            unsigned x = (unsigned)en.x;
            int pos = atomicAdd(&h[x >> 16], 1);
            unsigned bf = roundbf((unsigned)en.y);
            ivU[pos] = (bf << 16) | (x & 0xFFFFu);
        }
    } else {
        const int ib = b - UBK;
        const int s = base[b], n = cnt[b * CPAD];
        const int dbase = ib << ISH;
        h[t] = 0;
        __syncthreads();
        for (int p = s + t; p < s + n; p += 256)
            atomicAdd(&h[(unsigned)stI[p].x >> 17], 1);
        __syncthreads();
        int o0 = h[t];
        for (int off = 1; off < 256; off <<= 1) {
            int x0 = (t >= off) ? h[t - off] : 0;
            __syncthreads();
            h[t] += x0;
            __syncthreads();
        }
        int e0 = s + h[t] - o0;
        __syncthreads();
        h[t] = e0;
        if (dbase + t < ITEM_NUM) rpI[dbase + t] = e0;
        if (t == 0 && dbase + 256 >= ITEM_NUM) rpI[ITEM_NUM] = s + n;
        __syncthreads();
        for (int p = s + t; p < s + n; p += 256) {
            int2 en = stI[p];
            unsigned x = (unsigned)en.x;
            int pos = atomicAdd(&h[x >> 17], 1);
            unsigned v15 = roundbf((unsigned)en.y) & 0x7FFFu;
            ivI[pos] = (v15 << 17) | (x & 0x1FFFFu);
        }
    }
}

// ---------- gather hop core: fp8 source rows (64 B = 1 line), fp32 accumulate ----
template<bool ISU>
__device__ __forceinline__ void row_accum8(
    const int* __restrict__ rp, const unsigned* __restrict__ iv,
    const uint2* __restrict__ src, int row, int sub, int r, float* acc) {
    const int s = rp[row], e2 = rp[row + 1];
    float a0[8] = {0, 0, 0, 0, 0, 0, 0, 0};
    float a1[8] = {0, 0, 0, 0, 0, 0, 0, 0};
    int t = s + sub;
    for (; t + 8 < e2; t += 16) {
        const unsigned q0 = iv[t];
        const unsigned q1 = iv[t + 8];
        const float v0 = ISU ? __uint_as_float(q0 & 0xFFFF0000u)
                             : __uint_as_float((q0 >> 17) << 16);
        const float v1 = ISU ? __uint_as_float(q1 & 0xFFFF0000u)
                             : __uint_as_float((q1 >> 17) << 16);
        const int x0 = ISU ? (int)(q0 & 0xFFFFu) : (int)(q0 & 0x1FFFFu);
        const int x1 = ISU ? (int)(q1 & 0xFFFFu) : (int)(q1 & 0x1FFFFu);
        const uint2 b0 = src[x0 * 8 + r];
        const uint2 b1 = src[x1 * 8 + r];
        fma8(b0, v0, a0);
        fma8(b1, v1, a1);
    }
    if (t < e2) {
        const unsigned q0 = iv[t];
        const float v0 = ISU ? __uint_as_float(q0 & 0xFFFF0000u)
                             : __uint_as_float((q0 >> 17) << 16);
        const int x0 = ISU ? (int)(q0 & 0xFFFFu) : (int)(q0 & 0x1FFFFu);
        const uint2 b0 = src[x0 * 8 + r];
        fma8(b0, v0, a0);
    }
#pragma unroll
    for (int k = 0; k < 8; k++) acc[k] = a0[k] + a1[k];
#pragma unroll
    for (int off = 8; off <= 32; off <<= 1) {
#pragma unroll
        for (int k = 0; k < 8; k++) acc[k] += __shfl_xor(acc[k], off, 64);
    }
    // valid on sub==0
}

__global__ void __launch_bounds__(256) gather_hop_f8(
    const int* __restrict__ rpU, const unsigned* __restrict__ ivU,
    const uint2* __restrict__ srcForU, uint2* __restrict__ outU,
    const int* __restrict__ rpI, const unsigned* __restrict__ ivI,
    const uint2* __restrict__ srcForI, uint2* __restrict__ outI) {
    const int lane = threadIdx.x & 63;
    const int sub = lane >> 3;
    const int r = lane & 7;
    const int wave = blockIdx.x * 4 + (threadIdx.x >> 6);
    float acc[8];
    uint2* out; int row;
    if (wave < USER_NUM) {
        row = wave;
        row_accum8<true>(rpU, ivU, srcForU, row, sub, r, acc);
        out = outU;
    } else if (wave < USER_NUM + ITEM_NUM) {
        row = wave - USER_NUM;
        row_accum8<false>(rpI, ivI, srcForI, row, sub, r, acc);
        out = outI;
    } else return;
    if (sub == 0) out[row * 8 + r] = pack_fp8x8(acc);
}

__global__ void __launch_bounds__(256) gather_hop3(
    const int* __restrict__ rpU, const unsigned* __restrict__ ivU,
    const uint2* __restrict__ srcForU,
    const int* __restrict__ rpI, const unsigned* __restrict__ ivI,
    const uint2* __restrict__ srcForI,
    const float4* __restrict__ embU, const uint2* __restrict__ g1u,
    const uint2* __restrict__ g2u, float4* __restrict__ gcnU,
    const float4* __restrict__ embI, const uint2* __restrict__ g1i,
    const uint2* __restrict__ g2i, float4* __restrict__ gcnI) {
    const int lane = threadIdx.x & 63;
    const int sub = lane >> 3;
    const int r = lane & 7;
    const int wave = blockIdx.x * 4 + (threadIdx.x >> 6);
    float acc[8];
    const float4* emb; const uint2* g1; const uint2* g2; float4* gcn; int row;
    if (wave < USER_NUM) {
        row = wave;
        row_accum8<true>(rpU, ivU, srcForU, row, sub, r, acc);
        emb = embU; g1 = g1u; g2 = g2u; gcn = gcnU;
    } else if (wave < USER_NUM + ITEM_NUM) {
        row = wave - USER_NUM;
        row_accum8<false>(rpI, ivI, srcForI, row, sub, r, acc);
        emb = embI; g1 = g1i; g2 = g2i; gcn = gcnI;
    } else return;
    if (sub == 0) {
        const float C1 = 0.5f / FP8_SCALE;
        const float C2 = (1.0f / 3.0f) / FP8_SCALE;
        const float C3 = 0.25f / FP8_SCALE;
        float f1[8], f2[8];
        dec8(g1[row * 8 + r], f1);
        dec8(g2[row * 8 + r], f2);
        const float4 e0 = emb[row * 16 + 2 * r];
        const float4 e1 = emb[row * 16 + 2 * r + 1];
        float4 o0, o1;
        o0.x = e0.x + C1 * f1[0] + C2 * f2[0] + C3 * acc[0];
        o0.y = e0.y + C1 * f1[1] + C2 * f2[1] + C3 * acc[1];
        o0.z = e0.z + C1 * f1[2] + C2 * f2[2] + C3 * acc[2];
        o0.w = e0.w + C1 * f1[3] + C2 * f2[3] + C3 * acc[3];
        o1.x = e1.x + C1 * f1[4] + C2 * f2[4] + C3 * acc[4];
        o1.y = e1.y + C1 * f1[5] + C2 * f2[5] + C3 * acc[5];
        o1.z = e1.z + C1 * f1[6] + C2 * f2[6] + C3 * acc[6];
        o1.w = e1.w + C1 * f1[7] + C2 * f2[7] + C3 * acc[7];
        gcn[row * 16 + 2 * r] = o0;
        gcn[row * 16 + 2 * r + 1] = o1;
    }
}

// ---------- losses ----------
__global__ void __launch_bounds__(256) bpr_loss(
    const int* __restrict__ user, const int* __restrict__ itemI,
    const int* __restrict__ itemJ,
    const float4* __restrict__ gcnU4, const float4* __restrict__ gcnI4,
    float* __restrict__ accs) {
    const int lane = threadIdx.x & 63;
    const int sub = lane >> 4;
    const int r = lane & 15;
    const int W = blockIdx.x * 4 + (threadIdx.x >> 6);
    const int NW = gridDim.x * 4;
    float accB = 0.0f, accR = 0.0f;
    for (int g = W; g < NB / 4; g += NW) {
        const int samp = g * 4 + sub;
        const int uu = user[samp], vi = itemI[samp], vj = itemJ[samp];
        const float4 u  = gcnU4[uu * 16 + r];
        const float4 xi = gcnI4[vi * 16 + r];
        const float4 xj = gcnI4[vj * 16 + r];
        float pi = u.x * xi.x + u.y * xi.y + u.z * xi.z + u.w * xi.w;
        float pj = u.x * xj.x + u.y * xj.y + u.z * xj.z + u.w * xj.w;
        float rg = u.x * u.x + u.y * u.y + u.z * u.z + u.w * u.w
                 + xi.x * xi.x + xi.y * xi.y + xi.z * xi.z + xi.w * xi.w
                 + xj.x * xj.x + xj.y * xj.y + xj.z * xj.z + xj.w * xj.w;
#pragma unroll
        for (int off = 1; off <= 8; off <<= 1) {
            pi += __shfl_xor(pi, off, 64);
            pj += __shfl_xor(pj, off, 64);
            rg += __shfl_xor(rg, off, 64);
        }
        if (r == 0) {
            const float x = pi - pj;
            accB += fmaxf(-x, 0.0f) + log1pf(expf(-fabsf(x)));
            accR += rg;
        }
    }
    accB = waveReduceSum(accB);
    accR = waveReduceSum(accR);
    if (lane == 0) {
        const int slot = W & (NSLOT - 1);
        unsafeAtomicAdd(&accs[0 * NSLOT + slot], accB);
        unsafeAtomicAdd(&accs[1 * NSLOT + slot], accR);
    }
}

__global__ void __launch_bounds__(256) self_loss(
    const float4* __restrict__ oldU4, const float4* __restrict__ oldI4,
    const float4* __restrict__ gcnU4, const float4* __restrict__ gcnI4,
    const float* __restrict__ nU, const float* __restrict__ nI,
    float* __restrict__ accs) {
    const int lane = threadIdx.x & 63;
    const int sub = lane >> 4;
    const int r = lane & 15;
    const int W = blockIdx.x * 4 + (threadIdx.x >> 6);
    const int NW = gridDim.x * 4;
    const int ngroups = (USER_NUM + ITEM_NUM) / 4;
    float accU = 0.0f, accI = 0.0f;
    for (int g = W; g < ngroups; g += NW) {
        const int row = g * 4 + sub;
        const bool isU = row < USER_NUM;
        const int rr = isU ? row : row - USER_NUM;
        const float4 o  = isU ? oldU4[rr * 16 + r] : oldI4[rr * 16 + r];
        const float4 gg = isU ? gcnU4[rr * 16 + r] : gcnI4[rr * 16 + r];
        const float dx = o.x - gg.x, dy = o.y - gg.y;
        const float dz = o.z - gg.z, dw = o.w - gg.w;
        float s = dx * dx + dy * dy + dz * dz + dw * dw;
#pragma unroll
        for (int off = 1; off <= 8; off <<= 1)
            s += __shfl_xor(s, off, 64);
        if (r == 0) {
            const float val = sqrtf(s) * (isU ? nU[rr] : nI[rr]);
            if (isU) accU += val; else accI += val;
        }
    }
    accU = waveReduceSum(accU);
    accI = waveReduceSum(accI);
    if (lane == 0) {
        const int slot = W & (NSLOT - 1);
        unsafeAtomicAdd(&accs[2 * NSLOT + slot], accU);
        unsafeAtomicAdd(&accs[3 * NSLOT + slot], accI);
    }
}

__global__ void __launch_bounds__(64) finalize(const float* __restrict__ accs,
                                               float* __restrict__ out) {
    const int lane = threadIdx.x;
    float s[4];
#pragma unroll
    for (int k = 0; k < 4; k++) {
        float v = 0.0f;
        for (int j = lane; j < NSLOT; j += 64) v += accs[k * NSLOT + j];
        s[k] = waveReduceSum(v);
    }
    if (lane == 0) {
        const float loss_bpr = s[0] / NB + 1e-4f * (s[1] / NB);
        const float loss_self = s[2] / USER_NUM + s[3] / ITEM_NUM;
        out[0] = loss_bpr;
        out[1] = 100.0f * loss_self;
        out[2] = 1.0f;
        out[3] = 1.0f;
    }
}

extern "C" void kernel_launch(void* const* d_in, const int* in_sizes, int n_in,
                              void* d_out, int out_size, void* d_ws, size_t ws_size,
                              hipStream_t stream) {
    const int*   user     = (const int*)d_in[0];
    const int*   item_i   = (const int*)d_in[1];
    const int*   item_j   = (const int*)d_in[2];
    const int*   edge_u   = (const int*)d_in[3];
    const int*   edge_i   = (const int*)d_in[4];
    const float* edge_val = (const float*)d_in[5];
    const float* user_emb = (const float*)d_in[6];
    const float* item_emb = (const float*)d_in[7];
    const float* old_U    = (const float*)d_in[8];
    const float* old_I    = (const float*)d_in[9];
    const float* n_U      = (const float*)d_in[10];
    const float* n_I      = (const float*)d_in[11];
    float* out = (float*)d_out;

    char* base = (char*)d_ws;
    size_t off = 0;
    auto carve = [&](size_t bytes) {
        char* p = base + off;
        off += (bytes + 255) & ~(size_t)255;
        return p;
    };
    int*      coarseCnt = (int*)carve(NBK * CPAD * 4);  // padded: 1 count / 64B
    float*    accs      = (float*)carve(4 * NSLOT * 4);
    size_t zero_bytes = off;  // everything above must start zeroed
    int*      cbase = (int*)carve(NBK * 4);             // compact
    int*      ccur  = (int*)carve(NBK * CPAD * 4);      // padded cursors
    int*      rpU   = (int*)carve((USER_NUM + 1) * 4);
    int*      rpI   = (int*)carve((ITEM_NUM + 1) * 4);
    unsigned* ivU   = (unsigned*)carve((size_t)NEDGE * 4);
    unsigned* ivI   = (unsigned*)carve((size_t)NEDGE * 4);
    uint2*    ebU8  = (uint2*)carve((size_t)USER_NUM * DD);  // fp8 tables
    uint2*    ebI8  = (uint2*)carve((size_t)ITEM_NUM * DD);
    uint2*    g1u8  = (uint2*)carve((size_t)USER_NUM * DD);
    uint2*    g1i8  = (uint2*)carve((size_t)ITEM_NUM * DD);
    uint2*    g2u8  = (uint2*)carve((size_t)USER_NUM * DD);
    uint2*    g2i8  = (uint2*)carve((size_t)ITEM_NUM * DD);
    int2*     stU   = (int2*)carve((size_t)NEDGE * 8);   // staging, dead after binB
    int2*     stI   = (int2*)carve((size_t)NEDGE * 8);
    float* gcnU = (float*)stU;   // aliases staging (hop3 runs after binB)
    float* gcnI = (float*)stI;

    hipMemsetAsync(d_ws, 0, zero_bytes, stream);

    const dim3 blk(256);

    cvt8_kernel<<<(USER_NUM * 8 + 255) / 256, blk, 0, stream>>>(
        (const float4*)user_emb, ebU8, USER_NUM * 8);
    cvt8_kernel<<<(ITEM_NUM * 8 + 255) / 256, blk, 0, stream>>>(
        (const float4*)item_emb, ebI8, ITEM_NUM * 8);

    coarse_hist<<<HIST_GRID, blk, 0, stream>>>((const int4*)edge_u,
                                               (const int4*)edge_i, coarseCnt);
    coarse_scan<<<1, 512, 0, stream>>>(coarseCnt, cbase, ccur);
    binA<<<dim3(NTILE, 2), blk, 0, stream>>>(edge_u, edge_i, edge_val,
                                             ccur, stU, stI);
    binB<<<NBK, blk, 0, stream>>>(stU, stI, cbase, coarseCnt, rpU, rpI, ivU, ivI);

    const int rows = USER_NUM + ITEM_NUM;
    const int hop_grid = (rows + 3) / 4;

    gather_hop_f8<<<hop_grid, blk, 0, stream>>>(rpU, ivU, ebI8, g1u8,
                                                rpI, ivI, ebU8, g1i8);
    gather_hop_f8<<<hop_grid, blk, 0, stream>>>(rpU, ivU, g1i8, g2u8,
                                                rpI, ivI, g1u8, g2i8);
    gather_hop3<<<hop_grid, blk, 0, stream>>>(
        rpU, ivU, g2i8, rpI, ivI, g2u8,
        (const float4*)user_emb, g1u8, g2u8, (float4*)gcnU,
        (const float4*)item_emb, g1i8, g2i8, (float4*)gcnI);

    bpr_loss<<<128, blk, 0, stream>>>(user, item_i, item_j,
                                      (const float4*)gcnU, (const float4*)gcnI, accs);
    self_loss<<<256, blk, 0, stream>>>(
        (const float4*)old_U, (const float4*)old_I,
        (const float4*)gcnU, (const float4*)gcnI, n_U, n_I, accs);
    finalize<<<1, 64, 0, stream>>>(accs, out);
}